// Round 2
// baseline (99.717 us; speedup 1.0000x reference)
//
#include <hip/hip_runtime.h>
#include <stdint.h>

// Problem constants (B,C,H,W)=(4,128,64,128), R=4, D=9, out channels 81.
// Semantics (verified against the jnp.pad + %Hp wrap logic):
//   out[b, di*9+dj, h, w] = sum_c src[b,c,h,w] * tgt[b,c,h+di-8,w+dj-8],
//   zero when the shifted index leaves [0,H)x[0,W).
#define NB 4
#define NC 128
#define NH 64
#define NW 128
#define HW (NH * NW)      // 8192
#define ND 9
#define NOUT (ND * ND)    // 81

// Thread layout: grid = 4*9*32 = 1152 blocks of 64 threads (1 wave).
//   slice = blockIdx>>5 : b = slice/9, di = slice%9
//   h = (blockIdx&31)*2 + (lane>>5) ; w0 = (lane&31)*4  -> 4 pixels/thread
//   Each thread accumulates 9 dj x 4 px = 36 fp32 accumulators.
__global__ __launch_bounds__(64) void costvol_kernel(const float* __restrict__ src,
                                                     const float* __restrict__ tgt,
                                                     float* __restrict__ out) {
  const int lane = threadIdx.x;
  const int slice = blockIdx.x >> 5;       // 0..35
  const int di = slice % ND;               // 0..8
  const int b  = slice / ND;               // 0..3
  const int h  = ((blockIdx.x & 31) << 1) + (lane >> 5);  // 0..63
  const int w0 = (lane & 31) << 2;         // 0,4,...,124
  const int y  = h + di - 8;               // tgt row, may be <0 (then all-zero)

  float acc[ND][4];
#pragma unroll
  for (int dj = 0; dj < ND; ++dj)
#pragma unroll
    for (int k = 0; k < 4; ++k) acc[dj][k] = 0.0f;

  // Per-lane predicates for the three window quads (cols w0-8, w0-4, w0).
  const bool q0 = (w0 - 8) >= 0;
  const bool q1 = (w0 - 4) >= 0;

  if (y >= 0) {  // y <= 63 always (di-8 <= 0)
    const float* sp = src + (size_t)((b * NC) * NH + h) * NW + w0;  // + c*HW
    const float* tp = tgt + (size_t)((b * NC) * NH + y) * NW;       // + c*HW + col

#pragma unroll 4
    for (int c = 0; c < NC; ++c) {
      const float* spc = sp + (size_t)c * HW;
      const float* tpc = tp + (size_t)c * HW;

      const float4 sv = *(const float4*)spc;

      // Window cols w0-8 .. w0+3 (12 floats) as 3 aligned 16B quads.
      float t[12];
      {
        float4 t0, t1, t2;
        if (q0) t0 = *(const float4*)(tpc + w0 - 8);
        else    t0 = make_float4(0.f, 0.f, 0.f, 0.f);
        if (q1) t1 = *(const float4*)(tpc + w0 - 4);
        else    t1 = make_float4(0.f, 0.f, 0.f, 0.f);
        t2 = *(const float4*)(tpc + w0);   // always in-bounds (w0 <= 124)
        t[0] = t0.x; t[1] = t0.y; t[2]  = t0.z; t[3]  = t0.w;
        t[4] = t1.x; t[5] = t1.y; t[6]  = t1.z; t[7]  = t1.w;
        t[8] = t2.x; t[9] = t2.y; t[10] = t2.z; t[11] = t2.w;
      }

#pragma unroll
      for (int dj = 0; dj < ND; ++dj) {
        acc[dj][0] = fmaf(sv.x, t[dj + 0], acc[dj][0]);
        acc[dj][1] = fmaf(sv.y, t[dj + 1], acc[dj][1]);
        acc[dj][2] = fmaf(sv.z, t[dj + 2], acc[dj][2]);
        acc[dj][3] = fmaf(sv.w, t[dj + 3], acc[dj][3]);
      }
    }
  }

  // Epilogue: 9 aligned 16B stores (zeros when y<0 — every output written).
#pragma unroll
  for (int dj = 0; dj < ND; ++dj) {
    float4 o;
    o.x = acc[dj][0]; o.y = acc[dj][1]; o.z = acc[dj][2]; o.w = acc[dj][3];
    *(float4*)(out + (size_t)(((b * NOUT + di * ND + dj) * NH + h) * NW + w0)) = o;
  }
}

extern "C" void kernel_launch(void* const* d_in, const int* in_sizes, int n_in,
                              void* d_out, int out_size, void* d_ws, size_t ws_size,
                              hipStream_t stream) {
  const float* src = (const float*)d_in[0];
  const float* tgt = (const float*)d_in[1];
  float* out = (float*)d_out;
  costvol_kernel<<<dim3(NB * ND * 32), dim3(64), 0, stream>>>(src, tgt, out);
}

// Round 3
// 93.429 us; speedup vs baseline: 1.0673x; 1.0673x over previous
//
#include <hip/hip_runtime.h>
#include <stdint.h>

// Problem constants (B,C,H,W)=(4,128,64,128), R=4, D=9, out channels 81.
// out[b, di*9+dj, h, w] = sum_c src[b,c,h,w] * tgt[b,c,h+di-8,w+dj-8]
// (zero when the shifted index leaves [0,H)x[0,W)).
#define NB 4
#define NC 128
#define NH 64
#define NW 128
#define HW (NH * NW)      // 8192
#define ND 9
#define NOUT (ND * ND)    // 81
#define CPW 32            // channels per wave (4 waves x 32 = 128)

// grid = 4*9*32 = 1152 blocks of 256 threads (4 waves).
//   slice = blockIdx>>5 : b = slice/9, di = slice%9
//   hp = blockIdx&31 : h = hp*2 + (lane>>5) ; w0 = (lane&31)*4
//   wave handles channels [wave*32, wave*32+32); LDS-reduce at epilogue.
__global__ __launch_bounds__(256, 4) void costvol_kernel(const float* __restrict__ src,
                                                         const float* __restrict__ tgt,
                                                         float* __restrict__ out) {
  const int tid  = threadIdx.x;
  const int lane = tid & 63;
  const int wave = tid >> 6;
  const int slice = blockIdx.x >> 5;       // 0..35
  const int di = slice % ND;               // 0..8
  const int b  = slice / ND;               // 0..3
  const int hp = blockIdx.x & 31;          // 0..31
  const int h  = (hp << 1) + (lane >> 5);  // 0..63
  const int w0 = (lane & 31) << 2;         // 0,4,...,124
  const int y  = h + di - 8;               // tgt row; <0 -> all-zero lane

  float acc[ND][4];
#pragma unroll
  for (int dj = 0; dj < ND; ++dj)
#pragma unroll
    for (int k = 0; k < 4; ++k) acc[dj][k] = 0.0f;

  // Window quads at cols w0-8 / w0-4 are all-in or all-out of bounds.
  const bool q0 = w0 >= 8;
  const bool q1 = w0 >= 4;

  if (y >= 0) {
    const float* spc = src + (size_t)((b * NC + wave * CPW) * NH + h) * NW + w0;
    const float* tpc = tgt + (size_t)((b * NC + wave * CPW) * NH + y) * NW;

#pragma unroll 4
    for (int c = 0; c < CPW; ++c) {
      const float4 sv = *(const float4*)spc;

      float t[12];
      {
        float4 t0, t1, t2;
        if (q0) t0 = *(const float4*)(tpc + w0 - 8);
        else    t0 = make_float4(0.f, 0.f, 0.f, 0.f);
        if (q1) t1 = *(const float4*)(tpc + w0 - 4);
        else    t1 = make_float4(0.f, 0.f, 0.f, 0.f);
        t2 = *(const float4*)(tpc + w0);   // always in-bounds (w0 <= 124)
        t[0] = t0.x; t[1] = t0.y; t[2]  = t0.z; t[3]  = t0.w;
        t[4] = t1.x; t[5] = t1.y; t[6]  = t1.z; t[7]  = t1.w;
        t[8] = t2.x; t[9] = t2.y; t[10] = t2.z; t[11] = t2.w;
      }

#pragma unroll
      for (int dj = 0; dj < ND; ++dj) {
        acc[dj][0] = fmaf(sv.x, t[dj + 0], acc[dj][0]);
        acc[dj][1] = fmaf(sv.y, t[dj + 1], acc[dj][1]);
        acc[dj][2] = fmaf(sv.z, t[dj + 2], acc[dj][2]);
        acc[dj][3] = fmaf(sv.w, t[dj + 3], acc[dj][3]);
      }

      spc += HW;
      tpc += HW;
    }
  }

  // Cross-wave reduction: each wave dumps acc to LDS, then 256 threads
  // sum the 4 copies and store. 4*9*64*4 floats = 36 KB.
  __shared__ float lds[4][ND][64][4];
#pragma unroll
  for (int dj = 0; dj < ND; ++dj) {
    float4 v;
    v.x = acc[dj][0]; v.y = acc[dj][1]; v.z = acc[dj][2]; v.w = acc[dj][3];
    *(float4*)&lds[wave][dj][lane][0] = v;
  }
  __syncthreads();

  for (int s = tid; s < ND * 64; s += 256) {
    const int dj = s >> 6;
    const int l  = s & 63;
    const float4 r0 = *(const float4*)&lds[0][dj][l][0];
    const float4 r1 = *(const float4*)&lds[1][dj][l][0];
    const float4 r2 = *(const float4*)&lds[2][dj][l][0];
    const float4 r3 = *(const float4*)&lds[3][dj][l][0];
    float4 o;
    o.x = (r0.x + r1.x) + (r2.x + r3.x);
    o.y = (r0.y + r1.y) + (r2.y + r3.y);
    o.z = (r0.z + r1.z) + (r2.z + r3.z);
    o.w = (r0.w + r1.w) + (r2.w + r3.w);
    const int hh = (hp << 1) + (l >> 5);
    const int ww = (l & 31) << 2;
    *(float4*)(out + (size_t)(((b * NOUT + di * ND + dj) * NH + hh) * NW + ww)) = o;
  }
}

extern "C" void kernel_launch(void* const* d_in, const int* in_sizes, int n_in,
                              void* d_out, int out_size, void* d_ws, size_t ws_size,
                              hipStream_t stream) {
  const float* src = (const float*)d_in[0];
  const float* tgt = (const float*)d_in[1];
  float* out = (float*)d_out;
  costvol_kernel<<<dim3(NB * ND * 32), dim3(256), 0, stream>>>(src, tgt, out);
}